// Round 1
// baseline (430.650 us; speedup 1.0000x reference)
//
#include <hip/hip_runtime.h>
#include <stdint.h>
#include <stddef.h>

// ---------- types ----------
typedef __attribute__((ext_vector_type(8))) short s16x8;
typedef __attribute__((ext_vector_type(4))) short s16x4;
typedef __attribute__((ext_vector_type(4))) float f32x4;

#define S_LEN 2048
#define HID 2048
#define QKV_N 3072
#define NHEAD 32
#define NKVH 8

__device__ __forceinline__ unsigned short f2bf(float f) {
  union { float f; unsigned u; } a; a.f = f;
  unsigned u = a.u;
  u += 0x7fffu + ((u >> 16) & 1u);
  return (unsigned short)(u >> 16);
}
__device__ __forceinline__ float bf2f(unsigned short h) {
  union { unsigned u; float f; } a; a.u = ((unsigned)h) << 16;
  return a.f;
}
__device__ __forceinline__ void gl_lds16(const unsigned short* g, short* l) {
  __builtin_amdgcn_global_load_lds(
      (const __attribute__((address_space(1))) unsigned int*)g,
      (__attribute__((address_space(3))) unsigned int*)l, 16, 0, 0);
}

// ---------- 1) fp32 -> bf16 convert (X, Wq, Wk, Wv, Wo contiguous in ws) ----------
__global__ void k_convert(const float* __restrict__ x, const float* __restrict__ wq,
                          const float* __restrict__ wk, const float* __restrict__ wv,
                          const float* __restrict__ wo, unsigned short* __restrict__ dst) {
  const unsigned n4 = 18874368u / 4u;
  for (unsigned i = blockIdx.x * blockDim.x + threadIdx.x; i < n4;
       i += gridDim.x * blockDim.x) {
    unsigned e = i * 4u;
    const float* src; unsigned off;
    if (e < 8388608u)       { src = x;  off = e; }
    else if (e < 12582912u) { src = wq; off = e - 8388608u; }
    else if (e < 13631488u) { src = wk; off = e - 12582912u; }
    else if (e < 14680064u) { src = wv; off = e - 13631488u; }
    else                    { src = wo; off = e - 14680064u; }
    f32x4 v = *(const f32x4*)(src + off);
    s16x4 o;
    o[0] = (short)f2bf(v[0]); o[1] = (short)f2bf(v[1]);
    o[2] = (short)f2bf(v[2]); o[3] = (short)f2bf(v[3]);
    *(s16x4*)(dst + e) = o;
  }
}

// ---------- 2) RoPE cos/sin table [2048][32] fp32 each ----------
__global__ void k_rope_table(float* __restrict__ cost, float* __restrict__ sint) {
  int idx = blockIdx.x * 256 + threadIdx.x;  // 0..65535
  int i = idx & 31, s = idx >> 5;
  float inv = powf(10000.0f, -(float)(2 * i) / 64.0f);
  float ang = (float)s * inv;
  cost[idx] = cosf(ang);
  sint[idx] = sinf(ang);
}

// ---------- 3/7) GEMM: C[M,*] = A[M,2048] * W[*,2048]^T (+bias). m97-ish structure ----------
// MODE 0: QKV (segmented weights, bias, bf16 out, ldc=3072). MODE 1: fp32 out, ldc=2048.
template <int MODE>
__global__ __launch_bounds__(256) void k_gemm(
    const unsigned short* __restrict__ A,
    const unsigned short* __restrict__ W0, const unsigned short* __restrict__ W1,
    const unsigned short* __restrict__ W2,
    const float* __restrict__ b0, const float* __restrict__ b1, const float* __restrict__ b2,
    unsigned short* __restrict__ Cb, float* __restrict__ Cf) {
  __shared__ short lA[128 * 32];
  __shared__ short lB[128 * 32];
  const int K = 2048;
  int tid = threadIdx.x;
  int wave = tid >> 6, lane = tid & 63;
  int l15 = lane & 15, lg = lane >> 4;
  int tn = blockIdx.x, tm = blockIdx.y;
  const unsigned short* W; const float* bias = nullptr; int col0;
  if constexpr (MODE == 0) {
    if (tn < 16)      { W = W0; bias = b0; col0 = tn * 128; }
    else if (tn < 20) { W = W1; bias = b1; col0 = (tn - 16) * 128; }
    else              { W = W2; bias = b2; col0 = (tn - 20) * 128; }
  } else { W = W0; col0 = tn * 128; }
  int m0 = tm * 128;
  int wm = wave >> 1, wn = wave & 1;

  const unsigned short* gA0 = A + (size_t)(m0 + (tid >> 2)) * K + (tid & 3) * 8;
  const unsigned short* gA1 = gA0 + (size_t)64 * K;
  const unsigned short* gB0 = W + (size_t)(col0 + (tid >> 2)) * K + (tid & 3) * 8;
  const unsigned short* gB1 = gB0 + (size_t)64 * K;
  short* sA0 = &lA[wave * 512];
  short* sA1 = &lA[2048 + wave * 512];
  short* sB0 = &lB[wave * 512];
  short* sB1 = &lB[2048 + wave * 512];

  f32x4 acc[4][4];
#pragma unroll
  for (int m = 0; m < 4; ++m)
#pragma unroll
    for (int n = 0; n < 4; ++n) acc[m][n] = (f32x4){0.f, 0.f, 0.f, 0.f};

  for (int kt = 0; kt < K; kt += 32) {
    __syncthreads();
    gl_lds16(gA0 + kt, sA0);
    gl_lds16(gA1 + kt, sA1);
    gl_lds16(gB0 + kt, sB0);
    gl_lds16(gB1 + kt, sB1);
    asm volatile("s_waitcnt vmcnt(0)" ::: "memory");
    __syncthreads();
    s16x8 af[4], bfr[4];
    const short* pa = &lA[(wm * 64 + l15) * 32 + lg * 8];
    const short* pb = &lB[(wn * 64 + l15) * 32 + lg * 8];
#pragma unroll
    for (int m = 0; m < 4; ++m) af[m] = *(const s16x8*)(pa + m * 512);
#pragma unroll
    for (int n = 0; n < 4; ++n) bfr[n] = *(const s16x8*)(pb + n * 512);
#pragma unroll
    for (int m = 0; m < 4; ++m)
#pragma unroll
      for (int n = 0; n < 4; ++n)
        acc[m][n] = __builtin_amdgcn_mfma_f32_16x16x32_bf16(af[m], bfr[n], acc[m][n], 0, 0, 0);
  }

#pragma unroll
  for (int n = 0; n < 4; ++n) {
    int lcol = col0 + wn * 64 + n * 16 + l15;
    int gcol = tn * 128 + wn * 64 + n * 16 + l15;
    float bv = 0.f;
    if constexpr (MODE == 0) bv = bias[lcol];
#pragma unroll
    for (int m = 0; m < 4; ++m) {
      int row = m0 + wm * 64 + m * 16 + lg * 4;
#pragma unroll
      for (int r = 0; r < 4; ++r) {
        float v = acc[m][n][r] + bv;
        if constexpr (MODE == 0)
          Cb[(size_t)(row + r) * QKV_N + gcol] = f2bf(v);
        else
          Cf[(size_t)(row + r) * HID + gcol] = v;
      }
    }
  }
}

// ---------- 4) RoPE in-place on Q (cols 0..2047) and K (cols 2048..2559) ----------
__global__ void k_rope_apply(unsigned short* __restrict__ qkv,
                             const float* __restrict__ cost, const float* __restrict__ sint) {
  int t = blockIdx.x * blockDim.x + threadIdx.x;  // 0..655359
  int chunk = t & 3;
  int head = (t >> 2) % 40;
  int row = t / 160;
  int colb = head < 32 ? head * 64 : 2048 + (head - 32) * 64;
  int d0 = chunk * 8;
  int s = row & (S_LEN - 1);
  unsigned short* p = qkv + (size_t)row * QKV_N + colb;
  s16x8 lo = *(s16x8*)(p + d0);
  s16x8 hi = *(s16x8*)(p + 32 + d0);
  const float* cb = cost + s * 32 + d0;
  const float* sb = sint + s * 32 + d0;
  f32x4 c0 = *(const f32x4*)cb, c1 = *(const f32x4*)(cb + 4);
  f32x4 s0 = *(const f32x4*)sb, s1 = *(const f32x4*)(sb + 4);
  float cc[8] = {c0[0], c0[1], c0[2], c0[3], c1[0], c1[1], c1[2], c1[3]};
  float ss[8] = {s0[0], s0[1], s0[2], s0[3], s1[0], s1[1], s1[2], s1[3]};
  s16x8 nlo, nhi;
#pragma unroll
  for (int j = 0; j < 8; ++j) {
    float xl = bf2f((unsigned short)lo[j]);
    float xh = bf2f((unsigned short)hi[j]);
    nlo[j] = (short)f2bf(xl * cc[j] - xh * ss[j]);
    nhi[j] = (short)f2bf(xh * cc[j] + xl * ss[j]);
  }
  *(s16x8*)(p + d0) = nlo;
  *(s16x8*)(p + 32 + d0) = nhi;
}

// ---------- 5) V transpose: V[b*S+s][kv*64+d] -> Vt[((b*8+kv)*64+d)*2048 + s] ----------
__global__ void k_vtrans(const unsigned short* __restrict__ qkv, unsigned short* __restrict__ vt) {
  __shared__ unsigned short t[64][80];
  int ts = blockIdx.x & 63, td = blockIdx.x >> 6;
  int tid = threadIdx.x;
#pragma unroll
  for (int L = 0; L < 2; ++L) {
    int c = L * 256 + tid;
    int row = c >> 3, ch = c & 7;
    const unsigned short* src = qkv + (size_t)(ts * 64 + row) * QKV_N + 2560 + td * 64 + ch * 8;
    s16x8 v = *(const s16x8*)src;
    int cs = (ch * 8) ^ ((row >> 3) << 3);  // bank swizzle (involution, both sides)
    *(s16x8*)&t[row][cs] = v;
  }
  __syncthreads();
  int b = (ts * 64) >> 11;
  int s0 = (ts * 64) & (S_LEN - 1);
#pragma unroll
  for (int L = 0; L < 2; ++L) {
    int c = L * 256 + tid;
    int d = c >> 3, sc = c & 7;
    s16x8 o;
#pragma unroll
    for (int j = 0; j < 8; ++j) o[j] = (short)t[sc * 8 + j][d ^ (sc << 3)];
    unsigned short* dst = vt + ((size_t)((b * 8 + td) * 64 + d)) * 2048 + s0 + sc * 8;
    *(s16x8*)dst = o;
  }
}

// ---------- 6) GQA causal flash attention. 1 wave = 32 q rows. ----------
__global__ __launch_bounds__(256) void k_attn(const unsigned short* __restrict__ qkv,
                                              const unsigned short* __restrict__ vt,
                                              unsigned short* __restrict__ aout) {
  __shared__ unsigned short pl[4][32 * 80];
  int wave = threadIdx.x >> 6, lane = threadIdx.x & 63;
  int l15 = lane & 15, lg = lane >> 4;
  int wid = blockIdx.x * 4 + wave;      // 0..4095
  int qt = wid & 63;                    // 64 q-tiles of 32 rows
  int h = (wid >> 6) & 31;
  int b = wid >> 11;
  int q0 = qt * 32;
  int kvh = h >> 2;
  const unsigned short* qb_ = qkv + (size_t)(b * S_LEN) * QKV_N + h * 64;
  const unsigned short* kb_ = qkv + (size_t)(b * S_LEN) * QKV_N + 2048 + kvh * 64;
  const unsigned short* vb_ = vt + (size_t)((b * NKVH + kvh) * 64) * 2048;

  s16x8 aq[2][2];
#pragma unroll
  for (int m = 0; m < 2; ++m)
#pragma unroll
    for (int ks = 0; ks < 2; ++ks)
      aq[m][ks] = *(const s16x8*)(qb_ + (size_t)(q0 + m * 16 + l15) * QKV_N + ks * 32 + lg * 8);

  f32x4 acc[2][4];
  float mrow[2][4], lrow[2][4];
#pragma unroll
  for (int m = 0; m < 2; ++m) {
#pragma unroll
    for (int dt = 0; dt < 4; ++dt) acc[m][dt] = (f32x4){0.f, 0.f, 0.f, 0.f};
#pragma unroll
    for (int r = 0; r < 4; ++r) { mrow[m][r] = -3.0e38f; lrow[m][r] = 0.f; }
  }
  unsigned short* pw = &pl[wave][0];
  int kbmax = (q0 + 31) >> 6;

  for (int kb = 0; kb <= kbmax; ++kb) {
    // --- QK^T ---
    s16x8 bk[4][2];
#pragma unroll
    for (int nt = 0; nt < 4; ++nt)
#pragma unroll
      for (int ks = 0; ks < 2; ++ks)
        bk[nt][ks] = *(const s16x8*)(kb_ + (size_t)(kb * 64 + nt * 16 + l15) * QKV_N + ks * 32 + lg * 8);
    float pv[2][4][4];
    bool need_mask = (kb * 64 + 63) > q0;
#pragma unroll
    for (int m = 0; m < 2; ++m)
#pragma unroll
      for (int nt = 0; nt < 4; ++nt) {
        f32x4 z = (f32x4){0.f, 0.f, 0.f, 0.f};
        z = __builtin_amdgcn_mfma_f32_16x16x32_bf16(aq[m][0], bk[nt][0], z, 0, 0, 0);
        z = __builtin_amdgcn_mfma_f32_16x16x32_bf16(aq[m][1], bk[nt][1], z, 0, 0, 0);
#pragma unroll
        for (int r = 0; r < 4; ++r) {
          float v = z[r] * 0.125f;
          if (need_mask) {
            int qr = q0 + m * 16 + lg * 4 + r;
            int kc = kb * 64 + nt * 16 + l15;
            if (kc > qr) v = -3.0e38f;
          }
          pv[m][nt][r] = v;
        }
      }
    // --- online softmax (rows live in C-layout: row=(lg*4+r), col=l15) ---
#pragma unroll
    for (int m = 0; m < 2; ++m) {
#pragma unroll
      for (int r = 0; r < 4; ++r) {
        float v = fmaxf(fmaxf(pv[m][0][r], pv[m][1][r]), fmaxf(pv[m][2][r], pv[m][3][r]));
        v = fmaxf(v, __shfl_xor(v, 1));
        v = fmaxf(v, __shfl_xor(v, 2));
        v = fmaxf(v, __shfl_xor(v, 4));
        v = fmaxf(v, __shfl_xor(v, 8));
        float nm = fmaxf(mrow[m][r], v);
        float corr = __expf(mrow[m][r] - nm);
        mrow[m][r] = nm;
        float rs = 0.f;
#pragma unroll
        for (int nt = 0; nt < 4; ++nt) {
          float p = __expf(pv[m][nt][r] - nm);
          pv[m][nt][r] = p;
          rs += p;
        }
        rs += __shfl_xor(rs, 1); rs += __shfl_xor(rs, 2);
        rs += __shfl_xor(rs, 4); rs += __shfl_xor(rs, 8);
        lrow[m][r] = lrow[m][r] * corr + rs;
#pragma unroll
        for (int dt = 0; dt < 4; ++dt) acc[m][dt][r] *= corr;
      }
    }
    // --- P: C-layout -> LDS (swizzled) ---
#pragma unroll
    for (int m = 0; m < 2; ++m)
#pragma unroll
      for (int r = 0; r < 4; ++r) {
        int row = m * 16 + lg * 4 + r;
        int f = ((row >> 2) & 3) << 4;
#pragma unroll
        for (int nt = 0; nt < 4; ++nt) {
          int col = (nt * 16 + l15) ^ f;
          pw[row * 80 + col] = f2bf(pv[m][nt][r]);
        }
      }
    // --- PV ---
    s16x8 bv[4][2];
#pragma unroll
    for (int dt = 0; dt < 4; ++dt)
#pragma unroll
      for (int ks = 0; ks < 2; ++ks)
        bv[dt][ks] = *(const s16x8*)(vb_ + (size_t)(dt * 16 + l15) * 2048 + kb * 64 + ks * 32 + lg * 8);
#pragma unroll
    for (int m = 0; m < 2; ++m) {
      int row = m * 16 + l15;
      int f = ((row >> 2) & 3) << 4;
      s16x8 pa[2];
#pragma unroll
      for (int ks = 0; ks < 2; ++ks) {
        int cb = (ks * 32 + lg * 8) ^ f;
        pa[ks] = *(const s16x8*)(pw + row * 80 + cb);
      }
#pragma unroll
      for (int dt = 0; dt < 4; ++dt) {
        acc[m][dt] = __builtin_amdgcn_mfma_f32_16x16x32_bf16(pa[0], bv[dt][0], acc[m][dt], 0, 0, 0);
        acc[m][dt] = __builtin_amdgcn_mfma_f32_16x16x32_bf16(pa[1], bv[dt][1], acc[m][dt], 0, 0, 0);
      }
    }
  }
  // --- epilogue: O = acc / l ---
  unsigned short* ob = aout + (size_t)(b * S_LEN) * HID + h * 64;
#pragma unroll
  for (int m = 0; m < 2; ++m)
#pragma unroll
    for (int dt = 0; dt < 4; ++dt)
#pragma unroll
      for (int r = 0; r < 4; ++r) {
        float v = acc[m][dt][r] / lrow[m][r];
        ob[(size_t)(q0 + m * 16 + lg * 4 + r) * HID + dt * 16 + l15] = f2bf(v);
      }
}

// ---------- launch ----------
extern "C" void kernel_launch(void* const* d_in, const int* in_sizes, int n_in,
                              void* d_out, int out_size, void* d_ws, size_t ws_size,
                              hipStream_t stream) {
  const float* x  = (const float*)d_in[0];
  const float* qw = (const float*)d_in[1];
  const float* qb = (const float*)d_in[2];
  const float* kw = (const float*)d_in[3];
  const float* kbias = (const float*)d_in[4];
  const float* vw = (const float*)d_in[5];
  const float* vbias = (const float*)d_in[6];
  const float* ow = (const float*)d_in[7];

  unsigned short* Xb  = (unsigned short*)d_ws;          // 8388608
  unsigned short* Wqb = Xb + 8388608;                   // 4194304
  unsigned short* Wkb = Wqb + 4194304;                  // 1048576
  unsigned short* Wvb = Wkb + 1048576;                  // 1048576
  unsigned short* Wob = Wvb + 1048576;                  // 4194304
  unsigned short* QKV = Wob + 4194304;                  // 4096*3072
  unsigned short* VT  = QKV + 12582912;                 // 2*8*64*2048
  unsigned short* AO  = VT + 2097152;                   // 4096*2048
  float* COS = (float*)(AO + 8388608);                  // 65536 f32
  float* SIN = COS + 65536;

  k_convert<<<1024, 256, 0, stream>>>(x, qw, kw, vw, ow, Xb);
  k_rope_table<<<256, 256, 0, stream>>>(COS, SIN);
  k_gemm<0><<<dim3(24, 32), 256, 0, stream>>>(Xb, Wqb, Wkb, Wvb, qb, kbias, vbias, QKV, nullptr);
  k_rope_apply<<<2560, 256, 0, stream>>>(QKV, COS, SIN);
  k_vtrans<<<512, 256, 0, stream>>>(QKV, VT);
  k_attn<<<1024, 256, 0, stream>>>(QKV, VT, AO);
  k_gemm<1><<<dim3(16, 32), 256, 0, stream>>>(AO, Wob, nullptr, nullptr,
                                              nullptr, nullptr, nullptr, nullptr, (float*)d_out);
}

// Round 2
// 306.059 us; speedup vs baseline: 1.4071x; 1.4071x over previous
//
#include <hip/hip_runtime.h>
#include <stdint.h>
#include <stddef.h>

// ---------- types ----------
typedef __attribute__((ext_vector_type(8))) short s16x8;
typedef __attribute__((ext_vector_type(4))) short s16x4;
typedef __attribute__((ext_vector_type(4))) float f32x4;

#define S_LEN 2048
#define HID 2048
#define QKV_N 3072
#define NHEAD 32
#define NKVH 8

__device__ __forceinline__ unsigned short f2bf(float f) {
  union { float f; unsigned u; } a; a.f = f;
  unsigned u = a.u;
  u += 0x7fffu + ((u >> 16) & 1u);
  return (unsigned short)(u >> 16);
}
__device__ __forceinline__ float bf2f(unsigned short h) {
  union { unsigned u; float f; } a; a.u = ((unsigned)h) << 16;
  return a.f;
}
__device__ __forceinline__ void gl_lds16(const unsigned short* g, short* l) {
  __builtin_amdgcn_global_load_lds(
      (const __attribute__((address_space(1))) unsigned int*)g,
      (__attribute__((address_space(3))) unsigned int*)l, 16, 0, 0);
}

// ---------- 1) fp32 -> bf16 convert (X, Wq, Wk, Wv, Wo contiguous in ws) ----------
__global__ void k_convert(const float* __restrict__ x, const float* __restrict__ wq,
                          const float* __restrict__ wk, const float* __restrict__ wv,
                          const float* __restrict__ wo, unsigned short* __restrict__ dst) {
  const unsigned n4 = 18874368u / 4u;
  for (unsigned i = blockIdx.x * blockDim.x + threadIdx.x; i < n4;
       i += gridDim.x * blockDim.x) {
    unsigned e = i * 4u;
    const float* src; unsigned off;
    if (e < 8388608u)       { src = x;  off = e; }
    else if (e < 12582912u) { src = wq; off = e - 8388608u; }
    else if (e < 13631488u) { src = wk; off = e - 12582912u; }
    else if (e < 14680064u) { src = wv; off = e - 13631488u; }
    else                    { src = wo; off = e - 14680064u; }
    f32x4 v = *(const f32x4*)(src + off);
    s16x4 o;
    o[0] = (short)f2bf(v[0]); o[1] = (short)f2bf(v[1]);
    o[2] = (short)f2bf(v[2]); o[3] = (short)f2bf(v[3]);
    *(s16x4*)(dst + e) = o;
  }
}

// ---------- 2) RoPE cos/sin table [2048][32] fp32 each ----------
__global__ void k_rope_table(float* __restrict__ cost, float* __restrict__ sint) {
  int idx = blockIdx.x * 256 + threadIdx.x;  // 0..65535
  int i = idx & 31, s = idx >> 5;
  float inv = powf(10000.0f, -(float)(2 * i) / 64.0f);
  float ang = (float)s * inv;
  cost[idx] = cosf(ang);
  sint[idx] = sinf(ang);
}

// ---------- 3/7) GEMM: C[M,*] = A[M,2048] * W[*,2048]^T (+bias). m97-ish structure ----------
template <int MODE>
__global__ __launch_bounds__(256) void k_gemm(
    const unsigned short* __restrict__ A,
    const unsigned short* __restrict__ W0, const unsigned short* __restrict__ W1,
    const unsigned short* __restrict__ W2,
    const float* __restrict__ b0, const float* __restrict__ b1, const float* __restrict__ b2,
    unsigned short* __restrict__ Cb, float* __restrict__ Cf) {
  __shared__ short lA[128 * 32];
  __shared__ short lB[128 * 32];
  const int K = 2048;
  int tid = threadIdx.x;
  int wave = tid >> 6, lane = tid & 63;
  int l15 = lane & 15, lg = lane >> 4;
  int tn = blockIdx.x, tm = blockIdx.y;
  const unsigned short* W; const float* bias = nullptr; int col0;
  if constexpr (MODE == 0) {
    if (tn < 16)      { W = W0; bias = b0; col0 = tn * 128; }
    else if (tn < 20) { W = W1; bias = b1; col0 = (tn - 16) * 128; }
    else              { W = W2; bias = b2; col0 = (tn - 20) * 128; }
  } else { W = W0; col0 = tn * 128; }
  int m0 = tm * 128;
  int wm = wave >> 1, wn = wave & 1;

  const unsigned short* gA0 = A + (size_t)(m0 + (tid >> 2)) * K + (tid & 3) * 8;
  const unsigned short* gA1 = gA0 + (size_t)64 * K;
  const unsigned short* gB0 = W + (size_t)(col0 + (tid >> 2)) * K + (tid & 3) * 8;
  const unsigned short* gB1 = gB0 + (size_t)64 * K;
  short* sA0 = &lA[wave * 512];
  short* sA1 = &lA[2048 + wave * 512];
  short* sB0 = &lB[wave * 512];
  short* sB1 = &lB[2048 + wave * 512];

  f32x4 acc[4][4];
#pragma unroll
  for (int m = 0; m < 4; ++m)
#pragma unroll
    for (int n = 0; n < 4; ++n) acc[m][n] = (f32x4){0.f, 0.f, 0.f, 0.f};

  for (int kt = 0; kt < K; kt += 32) {
    __syncthreads();
    gl_lds16(gA0 + kt, sA0);
    gl_lds16(gA1 + kt, sA1);
    gl_lds16(gB0 + kt, sB0);
    gl_lds16(gB1 + kt, sB1);
    asm volatile("s_waitcnt vmcnt(0)" ::: "memory");
    __syncthreads();
    s16x8 af[4], bfr[4];
    const short* pa = &lA[(wm * 64 + l15) * 32 + lg * 8];
    const short* pb = &lB[(wn * 64 + l15) * 32 + lg * 8];
#pragma unroll
    for (int m = 0; m < 4; ++m) af[m] = *(const s16x8*)(pa + m * 512);
#pragma unroll
    for (int n = 0; n < 4; ++n) bfr[n] = *(const s16x8*)(pb + n * 512);
#pragma unroll
    for (int m = 0; m < 4; ++m)
#pragma unroll
      for (int n = 0; n < 4; ++n)
        acc[m][n] = __builtin_amdgcn_mfma_f32_16x16x32_bf16(af[m], bfr[n], acc[m][n], 0, 0, 0);
  }

#pragma unroll
  for (int n = 0; n < 4; ++n) {
    int lcol = col0 + wn * 64 + n * 16 + l15;
    int gcol = tn * 128 + wn * 64 + n * 16 + l15;
    float bv = 0.f;
    if constexpr (MODE == 0) bv = bias[lcol];
#pragma unroll
    for (int m = 0; m < 4; ++m) {
      int row = m0 + wm * 64 + m * 16 + lg * 4;
#pragma unroll
      for (int r = 0; r < 4; ++r) {
        float v = acc[m][n][r] + bv;
        if constexpr (MODE == 0)
          Cb[(size_t)(row + r) * QKV_N + gcol] = f2bf(v);
        else
          Cf[(size_t)(row + r) * HID + gcol] = v;
      }
    }
  }
}

// ---------- 4) RoPE in-place on Q (cols 0..2047) and K (cols 2048..2559) ----------
__global__ void k_rope_apply(unsigned short* __restrict__ qkv,
                             const float* __restrict__ cost, const float* __restrict__ sint) {
  int t = blockIdx.x * blockDim.x + threadIdx.x;  // 0..655359
  int chunk = t & 3;
  int head = (t >> 2) % 40;
  int row = t / 160;
  int colb = head < 32 ? head * 64 : 2048 + (head - 32) * 64;
  int d0 = chunk * 8;
  int s = row & (S_LEN - 1);
  unsigned short* p = qkv + (size_t)row * QKV_N + colb;
  s16x8 lo = *(s16x8*)(p + d0);
  s16x8 hi = *(s16x8*)(p + 32 + d0);
  const float* cb = cost + s * 32 + d0;
  const float* sb = sint + s * 32 + d0;
  f32x4 c0 = *(const f32x4*)cb, c1 = *(const f32x4*)(cb + 4);
  f32x4 s0 = *(const f32x4*)sb, s1 = *(const f32x4*)(sb + 4);
  float cc[8] = {c0[0], c0[1], c0[2], c0[3], c1[0], c1[1], c1[2], c1[3]};
  float ss[8] = {s0[0], s0[1], s0[2], s0[3], s1[0], s1[1], s1[2], s1[3]};
  s16x8 nlo, nhi;
#pragma unroll
  for (int j = 0; j < 8; ++j) {
    float xl = bf2f((unsigned short)lo[j]);
    float xh = bf2f((unsigned short)hi[j]);
    nlo[j] = (short)f2bf(xl * cc[j] - xh * ss[j]);
    nhi[j] = (short)f2bf(xh * cc[j] + xl * ss[j]);
  }
  *(s16x8*)(p + d0) = nlo;
  *(s16x8*)(p + 32 + d0) = nhi;
}

// ---------- 5) V transpose ----------
__global__ void k_vtrans(const unsigned short* __restrict__ qkv, unsigned short* __restrict__ vt) {
  __shared__ unsigned short t[64][80];
  int ts = blockIdx.x & 63, td = blockIdx.x >> 6;
  int tid = threadIdx.x;
#pragma unroll
  for (int L = 0; L < 2; ++L) {
    int c = L * 256 + tid;
    int row = c >> 3, ch = c & 7;
    const unsigned short* src = qkv + (size_t)(ts * 64 + row) * QKV_N + 2560 + td * 64 + ch * 8;
    s16x8 v = *(const s16x8*)src;
    int cs = (ch * 8) ^ ((row >> 3) << 3);
    *(s16x8*)&t[row][cs] = v;
  }
  __syncthreads();
  int b = (ts * 64) >> 11;
  int s0 = (ts * 64) & (S_LEN - 1);
#pragma unroll
  for (int L = 0; L < 2; ++L) {
    int c = L * 256 + tid;
    int d = c >> 3, sc = c & 7;
    s16x8 o;
#pragma unroll
    for (int j = 0; j < 8; ++j) o[j] = (short)t[sc * 8 + j][d ^ (sc << 3)];
    unsigned short* dst = vt + ((size_t)((b * 8 + td) * 64 + d)) * 2048 + s0 + sc * 8;
    *(s16x8*)dst = o;
  }
}

// ---------- 6) attention tile step (32 q-rows vs 64 keys) ----------
__device__ __forceinline__ void attn_step(
    int q0, int kb, int l15, int lg,
    const s16x8 aq[2][2], const s16x8 bk[4][2], const s16x8 bv[4][2],
    f32x4 acc[2][4], float mrow[2][4], float lrow[2][4],
    unsigned short* pw) {
  float pv[2][4][4];
  bool need_mask = (kb * 64 + 63) > q0;
  __builtin_amdgcn_s_setprio(1);
#pragma unroll
  for (int m = 0; m < 2; ++m)
#pragma unroll
    for (int nt = 0; nt < 4; ++nt) {
      f32x4 z = (f32x4){0.f, 0.f, 0.f, 0.f};
      z = __builtin_amdgcn_mfma_f32_16x16x32_bf16(aq[m][0], bk[nt][0], z, 0, 0, 0);
      z = __builtin_amdgcn_mfma_f32_16x16x32_bf16(aq[m][1], bk[nt][1], z, 0, 0, 0);
#pragma unroll
      for (int r = 0; r < 4; ++r) {
        float v = z[r] * 0.125f;
        if (need_mask) {
          int qr = q0 + m * 16 + lg * 4 + r;
          int kc = kb * 64 + nt * 16 + l15;
          if (kc > qr) v = -3.0e38f;
        }
        pv[m][nt][r] = v;
      }
    }
  __builtin_amdgcn_s_setprio(0);
  // online softmax: rows in C-layout (row = lg*4+r, col = l15)
#pragma unroll
  for (int m = 0; m < 2; ++m) {
#pragma unroll
    for (int r = 0; r < 4; ++r) {
      float v = fmaxf(fmaxf(pv[m][0][r], pv[m][1][r]), fmaxf(pv[m][2][r], pv[m][3][r]));
      v = fmaxf(v, __shfl_xor(v, 1));
      v = fmaxf(v, __shfl_xor(v, 2));
      v = fmaxf(v, __shfl_xor(v, 4));
      v = fmaxf(v, __shfl_xor(v, 8));
      float nm = fmaxf(mrow[m][r], v);
      float corr = __expf(mrow[m][r] - nm);
      mrow[m][r] = nm;
      float rs = 0.f;
#pragma unroll
      for (int nt = 0; nt < 4; ++nt) {
        float p = __expf(pv[m][nt][r] - nm);
        pv[m][nt][r] = p;
        rs += p;
      }
      rs += __shfl_xor(rs, 1); rs += __shfl_xor(rs, 2);
      rs += __shfl_xor(rs, 4); rs += __shfl_xor(rs, 8);
      lrow[m][r] = lrow[m][r] * corr + rs;
#pragma unroll
      for (int dt = 0; dt < 4; ++dt) acc[m][dt][r] *= corr;
    }
  }
  // P: C-layout -> LDS (bank-swizzled)
#pragma unroll
  for (int m = 0; m < 2; ++m)
#pragma unroll
    for (int r = 0; r < 4; ++r) {
      int row = m * 16 + lg * 4 + r;
      int f = ((row >> 2) & 3) << 4;
#pragma unroll
      for (int nt = 0; nt < 4; ++nt) {
        int col = (nt * 16 + l15) ^ f;
        pw[row * 80 + col] = f2bf(pv[m][nt][r]);
      }
    }
  // PV
#pragma unroll
  for (int m = 0; m < 2; ++m) {
    int row = m * 16 + l15;
    int f = ((row >> 2) & 3) << 4;
    s16x8 pa[2];
#pragma unroll
    for (int ks = 0; ks < 2; ++ks) {
      int cb = (ks * 32 + lg * 8) ^ f;
      pa[ks] = *(const s16x8*)(pw + row * 80 + cb);
    }
    __builtin_amdgcn_s_setprio(1);
#pragma unroll
    for (int dt = 0; dt < 4; ++dt) {
      acc[m][dt] = __builtin_amdgcn_mfma_f32_16x16x32_bf16(pa[0], bv[dt][0], acc[m][dt], 0, 0, 0);
      acc[m][dt] = __builtin_amdgcn_mfma_f32_16x16x32_bf16(pa[1], bv[dt][1], acc[m][dt], 0, 0, 0);
    }
    __builtin_amdgcn_s_setprio(0);
  }
}

// ---------- 6) GQA causal flash attention, mirror-paired q-tiles ----------
// block = {4 heads of one KV group} x {pair index ip, batch b}; wave w -> head hg*4+w.
// wave handles q-tiles ip and 63-ip (shared K/V frags, perfectly balanced: 33 tile-steps).
__global__ __launch_bounds__(256, 2) void k_attn(const unsigned short* __restrict__ qkv,
                                                 const unsigned short* __restrict__ vt,
                                                 unsigned short* __restrict__ aout) {
  __shared__ unsigned short pl[4][32 * 80];
  int wave = threadIdx.x >> 6, lane = threadIdx.x & 63;
  int l15 = lane & 15, lg = lane >> 4;
  int bi = blockIdx.x;              // 0..511
  int ip = bi & 31;                 // pair index
  int hg = (bi >> 5) & 7;           // kv head group
  int b  = bi >> 8;
  int h  = hg * 4 + wave;
  const unsigned short* qb_ = qkv + (size_t)(b * S_LEN) * QKV_N + h * 64;
  const unsigned short* kb_ = qkv + (size_t)(b * S_LEN) * QKV_N + 2048 + hg * 64;
  const unsigned short* vb_ = vt + (size_t)((b * NKVH + hg) * 64) * 2048;

  int q0A = ip * 32;
  int q0B = (63 - ip) * 32;
  int kbmaxA = (q0A + 31) >> 6;
  int kbmaxB = (q0B + 31) >> 6;

  s16x8 aqA[2][2], aqB[2][2];
#pragma unroll
  for (int m = 0; m < 2; ++m)
#pragma unroll
    for (int ks = 0; ks < 2; ++ks) {
      aqA[m][ks] = *(const s16x8*)(qb_ + (size_t)(q0A + m * 16 + l15) * QKV_N + ks * 32 + lg * 8);
      aqB[m][ks] = *(const s16x8*)(qb_ + (size_t)(q0B + m * 16 + l15) * QKV_N + ks * 32 + lg * 8);
    }

  f32x4 accA[2][4], accB[2][4];
  float mrA[2][4], lrA[2][4], mrB[2][4], lrB[2][4];
#pragma unroll
  for (int m = 0; m < 2; ++m) {
#pragma unroll
    for (int dt = 0; dt < 4; ++dt) {
      accA[m][dt] = (f32x4){0.f, 0.f, 0.f, 0.f};
      accB[m][dt] = (f32x4){0.f, 0.f, 0.f, 0.f};
    }
#pragma unroll
    for (int r = 0; r < 4; ++r) {
      mrA[m][r] = -3.0e38f; lrA[m][r] = 0.f;
      mrB[m][r] = -3.0e38f; lrB[m][r] = 0.f;
    }
  }
  unsigned short* pw = &pl[wave][0];

  for (int kb = 0; kb <= kbmaxB; ++kb) {
    // K fragments (shared by both tiles)
    s16x8 bk[4][2];
#pragma unroll
    for (int nt = 0; nt < 4; ++nt)
#pragma unroll
      for (int ks = 0; ks < 2; ++ks)
        bk[nt][ks] = *(const s16x8*)(kb_ + (size_t)(kb * 64 + nt * 16 + l15) * QKV_N + ks * 32 + lg * 8);
    // V fragments issued early (overlap with QK^T + softmax)
    s16x8 bv[4][2];
#pragma unroll
    for (int dt = 0; dt < 4; ++dt)
#pragma unroll
      for (int ks = 0; ks < 2; ++ks)
        bv[dt][ks] = *(const s16x8*)(vb_ + (size_t)(dt * 16 + l15) * 2048 + kb * 64 + ks * 32 + lg * 8);

    attn_step(q0B, kb, l15, lg, aqB, bk, bv, accB, mrB, lrB, pw);
    if (kb <= kbmaxA)
      attn_step(q0A, kb, l15, lg, aqA, bk, bv, accA, mrA, lrA, pw);
  }

  unsigned short* ob = aout + (size_t)(b * S_LEN) * HID + h * 64;
#pragma unroll
  for (int m = 0; m < 2; ++m)
#pragma unroll
    for (int dt = 0; dt < 4; ++dt)
#pragma unroll
      for (int r = 0; r < 4; ++r) {
        float vB = accB[m][dt][r] / lrB[m][r];
        ob[(size_t)(q0B + m * 16 + lg * 4 + r) * HID + dt * 16 + l15] = f2bf(vB);
        float vA = accA[m][dt][r] / lrA[m][r];
        ob[(size_t)(q0A + m * 16 + lg * 4 + r) * HID + dt * 16 + l15] = f2bf(vA);
      }
}

// ---------- launch ----------
extern "C" void kernel_launch(void* const* d_in, const int* in_sizes, int n_in,
                              void* d_out, int out_size, void* d_ws, size_t ws_size,
                              hipStream_t stream) {
  const float* x  = (const float*)d_in[0];
  const float* qw = (const float*)d_in[1];
  const float* qb = (const float*)d_in[2];
  const float* kw = (const float*)d_in[3];
  const float* kbias = (const float*)d_in[4];
  const float* vw = (const float*)d_in[5];
  const float* vbias = (const float*)d_in[6];
  const float* ow = (const float*)d_in[7];

  unsigned short* Xb  = (unsigned short*)d_ws;          // 8388608
  unsigned short* Wqb = Xb + 8388608;                   // 4194304
  unsigned short* Wkb = Wqb + 4194304;                  // 1048576
  unsigned short* Wvb = Wkb + 1048576;                  // 1048576
  unsigned short* Wob = Wvb + 1048576;                  // 4194304
  unsigned short* QKV = Wob + 4194304;                  // 4096*3072
  unsigned short* VT  = QKV + 12582912;                 // 2*8*64*2048
  unsigned short* AO  = VT + 2097152;                   // 4096*2048
  float* COS = (float*)(AO + 8388608);                  // 65536 f32
  float* SIN = COS + 65536;

  k_convert<<<1024, 256, 0, stream>>>(x, qw, kw, vw, ow, Xb);
  k_rope_table<<<256, 256, 0, stream>>>(COS, SIN);
  k_gemm<0><<<dim3(24, 32), 256, 0, stream>>>(Xb, Wqb, Wkb, Wvb, qb, kbias, vbias, QKV, nullptr);
  k_rope_apply<<<2560, 256, 0, stream>>>(QKV, COS, SIN);
  k_vtrans<<<512, 256, 0, stream>>>(QKV, VT);
  k_attn<<<512, 256, 0, stream>>>(QKV, VT, AO);
  k_gemm<1><<<dim3(16, 32), 256, 0, stream>>>(AO, Wob, nullptr, nullptr,
                                              nullptr, nullptr, nullptr, nullptr, (float*)d_out);
}